// Round 13
// baseline (1896.281 us; speedup 1.0000x reference)
//
#include <hip/hip_runtime.h>
#include <hip/hip_fp16.h>
#include <hip/hip_cooperative_groups.h>
#include <math.h>

#define NN 50000
#define EE 800000
#define HIDDEN 128
#define NGRAPH 50
#define GEMM_TILES ((NN + 63) / 64)
#define MEGA_BLOCKS 1024

typedef _Float16 half8 __attribute__((ext_vector_type(8)));
typedef float f32x4 __attribute__((ext_vector_type(4)));

namespace cg = cooperative_groups;

struct MegaArgs {
    const float* x_in; const _Float16* wt;
    const float* bq; const float* bk; const float* bv; const float* bs;
    const float* We; const float* be; const float* Wb;
    const float* gamma; const float* beta;
    const float* Wout; const float* bout; const float* obias;
    const int* esrc; const float* eat2; const int* row_ptr; const int* batch;
    float* qb; unsigned int* kvb; float* xrb; float* xbuf;
    float* bn_acc3; float* gsum; int* gcnt; float* out;
};

// ---------------- CSR degree count + weight transpose (union grid) ----------------
__global__ void k_degprep(const int* __restrict__ eidx, int* __restrict__ cnt,
                          const float* __restrict__ Wq, const float* __restrict__ Wk,
                          const float* __restrict__ Wv, const float* __restrict__ Ws,
                          _Float16* __restrict__ wt) {
    int b = blockIdx.x;
    int t = threadIdx.x;
    if (b < 3125) {
        int e = b * 256 + t;
        if (e < EE) atomicAdd(&cnt[eidx[EE + e]], 1);
    } else {
        int idx = (b - 3125) * 256 + t;   // 12 * 16384 fp16 transposed weights
        if (idx < 12 * 16384) {
            int mat = idx >> 14;
            int l = mat >> 2, w = mat & 3;
            int nk = idx & 16383;
            int n = nk >> 7, k = nk & 127;
            const float* W = (w == 0 ? Wq : w == 1 ? Wk : w == 2 ? Wv : Ws) + (size_t)l * 16384;
            wt[idx] = (_Float16)W[k * 128 + n];
        }
    }
}

// scan + housekeeping
__global__ void k_scan(int* __restrict__ cnt, int* __restrict__ row_ptr,
                       float* __restrict__ bn_acc3, float* __restrict__ gsum,
                       int* __restrict__ gcnt) {
    __shared__ int wsum[16];
    __shared__ int carry_s;
    int t = threadIdx.x;
    int lane = t & 63, w = t >> 6;
    if (t < 768) bn_acc3[t] = 0.f;
    if (t < 64) { gsum[t] = 0.f; gcnt[t] = 0; }
    if (t == 0) carry_s = 0;
    __syncthreads();
    for (int base = 0; base < NN; base += 4096) {
        int i0 = base + t * 4;
        int v[4];
#pragma unroll
        for (int j = 0; j < 4; j++) v[j] = (i0 + j < NN) ? cnt[i0 + j] : 0;
        int s4 = v[0] + v[1] + v[2] + v[3];
        int s = s4;
#pragma unroll
        for (int o = 1; o < 64; o <<= 1) {
            int u = __shfl_up(s, o);
            if (lane >= o) s += u;
        }
        if (lane == 63) wsum[w] = s;
        __syncthreads();
        if (w == 0) {
            int ws = (lane < 16) ? wsum[lane] : 0;
#pragma unroll
            for (int o = 1; o < 16; o <<= 1) {
                int u = __shfl_up(ws, o);
                if (lane >= o) ws += u;
            }
            if (lane < 16) wsum[lane] = ws;
        }
        __syncthreads();
        int wpre = (w == 0) ? 0 : wsum[w - 1];
        int run = carry_s + wpre + s - s4;
#pragma unroll
        for (int j = 0; j < 4; j++) {
            if (i0 + j < NN) { row_ptr[i0 + j] = run; cnt[i0 + j] = 0; run += v[j]; }
        }
        __syncthreads();
        if (t == 0) carry_s += wsum[15];
        __syncthreads();
    }
    if (t == 0) row_ptr[NN] = carry_s;
}

__global__ void k_scatter(const int* __restrict__ eidx, const float* __restrict__ eattr,
                          const int* __restrict__ row_ptr,
                          int* __restrict__ cur, int* __restrict__ esrc, float* __restrict__ eat2) {
    int e = blockIdx.x * blockDim.x + threadIdx.x;
    if (e < EE) {
        int d = eidx[EE + e];
        int s = eidx[e];
        int p = atomicAdd(&cur[d], 1);
        int pos = row_ptr[d] + p;
        esrc[pos] = s;
        float2 ea = *(const float2*)&eattr[2 * (size_t)e];
        *(float2*)&eat2[2 * (size_t)pos] = ea;
    }
}

// ---------------- shared device phase functions ----------------
__device__ __forceinline__ void compute_ab(const float* bn_acc, const float* gam,
                                           const float* bet, float* ab_s, int t) {
    if (t < 128) {
        float mu = bn_acc[t] * (1.f / NN);
        float var = bn_acc[128 + t] * (1.f / NN) - mu * mu;
        float inv = rsqrtf(var + 1e-5f);
        float a = inv * gam[t];
        ab_s[t] = a;
        ab_s[128 + t] = bet[t] - mu * a;
    }
}

// GEMM phase: grid-strided 64-row tiles. ab_s must be ready (synced) if use_ab.
__device__ __forceinline__ void gemm_phase(const MegaArgs& A, int l,
                                           _Float16 (*xs)[136], const float* ab_s,
                                           int use_ab, int bid, int gstride) {
    int t = threadIdx.x;
    int lane = t & 63, wid = t >> 6;
    const _Float16* wtl = A.wt + (size_t)l * 65536;
    const float* bqL = A.bq + l * 128;
    const float* bkL = A.bk + l * 128;
    const float* bvL = A.bv + l * 128;
    const float* bsL = A.bs + l * 128;
    const float* X = (l == 0) ? A.x_in : A.xbuf;
    int quad = lane >> 4, l15 = lane & 15;
    int mrow = wid * 16;
    for (int tile = bid; tile < GEMM_TILES; tile += gstride) {
        int m0 = tile * 64;
#pragma unroll
        for (int i = 0; i < 8; ++i) {
            int f = t + 256 * i;          // float4 index within 64x32
            int r = f >> 5, c4 = (f & 31) << 2;
            float4 val = make_float4(0.f, 0.f, 0.f, 0.f);
            if (m0 + r < NN) val = *(const float4*)&X[(size_t)(m0 + r) * 128 + c4];
            if (use_ab) {
                float4 a = *(const float4*)&ab_s[c4];
                float4 bb = *(const float4*)&ab_s[128 + c4];
                float z;
                z = fmaf(val.x, a.x, bb.x); val.x = z > 0.f ? z : expm1f(z);
                z = fmaf(val.y, a.y, bb.y); val.y = z > 0.f ? z : expm1f(z);
                z = fmaf(val.z, a.z, bb.z); val.z = z > 0.f ? z : expm1f(z);
                z = fmaf(val.w, a.w, bb.w); val.w = z > 0.f ? z : expm1f(z);
            }
            _Float16* dst = &xs[r][c4];
            dst[0] = (_Float16)val.x; dst[1] = (_Float16)val.y;
            dst[2] = (_Float16)val.z; dst[3] = (_Float16)val.w;
        }
        __syncthreads();
        half8 afrag[4];
#pragma unroll
        for (int kk = 0; kk < 4; kk++)
            afrag[kk] = *(const half8*)&xs[mrow + l15][kk * 32 + quad * 8];
#pragma unroll
        for (int nt = 0; nt < 8; nt++) {
            int c = nt * 16 + l15;
            f32x4 acc[4];
#pragma unroll
            for (int w = 0; w < 4; w++) acc[w] = (f32x4){0.f, 0.f, 0.f, 0.f};
#pragma unroll
            for (int kk = 0; kk < 4; kk++) {
                half8 bf[4];
#pragma unroll
                for (int w = 0; w < 4; w++)
                    bf[w] = *(const half8*)&wtl[(size_t)w * 16384 + c * 128 + kk * 32 + quad * 8];
#pragma unroll
                for (int w = 0; w < 4; w++)
                    acc[w] = __builtin_amdgcn_mfma_f32_16x16x32_f16(afrag[kk], bf[w], acc[w], 0, 0, 0);
            }
            float bqv = bqL[c], bkv = bkL[c], bvv = bvL[c], bsv = bsL[c];
            int nodebase = m0 + mrow + quad * 4;
#pragma unroll
            for (int r = 0; r < 4; r++) {
                int node = nodebase + r;
                bool ok = node < NN;
                float qv = acc[0][r] + bqv;
                float xv = acc[3][r] + bsv;
                float kf = acc[1][r] + bkv;
                float vf = acc[2][r] + bvv;
                float kf1 = __shfl_xor(kf, 1);
                float vf1 = __shfl_xor(vf, 1);
                if (ok) {
                    A.qb[(size_t)node * 128 + c] = qv;
                    A.xrb[(size_t)node * 128 + c] = xv;
                    if (!(lane & 1)) {
                        int w2 = __builtin_amdgcn_cvt_pk_fp8_f32(kf, kf1, 0, false);
                        w2 = __builtin_amdgcn_cvt_pk_fp8_f32(vf, vf1, w2, true);
                        A.kvb[(size_t)node * 64 + (c >> 1)] = (unsigned int)w2;
                    }
                }
            }
        }
        __syncthreads();   // xs reused next tile
    }
}

// ATTN phase: wave-per-node, groups of 8 gathers (r10-proven). ss = 4*256 floats smem.
__device__ __forceinline__ void attn_phase(const MegaArgs& A, int l, float* ss,
                                           int bid, int gstride) {
    int t = threadIdx.x;
    int lane = t & 63, wid = t >> 6;
    const float* WeL = A.We + (size_t)l * 256;
    const float* beL_p = A.be + l * 128;
    const float* WbL = A.Wb + (size_t)l * 384;
    float* bn_accum = A.bn_acc3 + l * 256;
    int gwave = bid * 4 + wid;
    int nwaves = gstride * 4;
    int ch = lane * 2;
    float2 we0 = *(const float2*)&WeL[ch];
    float2 we1 = *(const float2*)&WeL[128 + ch];
    float2 beL = *(const float2*)&beL_p[ch];
    float2 wb_o = *(const float2*)&WbL[ch];
    float2 wb_r = *(const float2*)&WbL[128 + ch];
    float2 wb_d = *(const float2*)&WbL[256 + ch];
    const float scale = 0.17677669529663687f;   // 1/sqrt(32)
    float bnsx = 0.f, bnsy = 0.f, bnqx = 0.f, bnqy = 0.f;

    for (int n = gwave; n < NN; n += nwaves) {
        int rs = __builtin_amdgcn_readfirstlane(A.row_ptr[n]);
        int re = __builtin_amdgcn_readfirstlane(A.row_ptr[n + 1]);
        float2 qv = *(const float2*)&A.qb[(size_t)n * 128 + ch];
        float den = 0.f;
        float ax = 0.f, ay = 0.f;

        auto edge = [&](float eax, float eay, unsigned int w8) {
            auto kf = __builtin_amdgcn_cvt_pk_f32_fp8((int)w8, false);
            auto vf = __builtin_amdgcn_cvt_pk_f32_fp8((int)w8, true);
            float ex_ = fmaf(eax, we0.x, fmaf(eay, we1.x, beL.x));
            float ey_ = fmaf(eax, we0.y, fmaf(eay, we1.y, beL.y));
            float p = qv.x * (kf[0] + ex_) + qv.y * (kf[1] + ey_);
            p += __shfl_xor(p, 1);
            p += __shfl_xor(p, 2);
            p += __shfl_xor(p, 4);
            p += __shfl_xor(p, 8);
            float exv = __expf(p * scale);
            den += exv;
            ax = fmaf(exv, vf[0] + ex_, ax);
            ay = fmaf(exv, vf[1] + ey_, ay);
        };

        for (int cb = rs; cb < re; cb += 64) {
            int cnum = re - cb; if (cnum > 64) cnum = 64;
            int mi = cb + lane;
            int sv = 0;
            float2 av = make_float2(0.f, 0.f);
            if (mi < re) {
                sv = A.esrc[mi];
                av = *(const float2*)&A.eat2[2 * (size_t)mi];
            }
            int base = 0;
            for (; base + 8 <= cnum; base += 8) {
                int s[8]; float eax[8], eay[8];
#pragma unroll
                for (int j = 0; j < 8; j++) {
                    s[j] = __shfl(sv, base + j);
                    eax[j] = __shfl(av.x, base + j);
                    eay[j] = __shfl(av.y, base + j);
                }
                unsigned int kk[8];
#pragma unroll
                for (int j = 0; j < 8; j++)
                    kk[j] = A.kvb[(size_t)s[j] * 64 + lane];
#pragma unroll
                for (int j = 0; j < 8; j++) edge(eax[j], eay[j], kk[j]);
            }
            for (; base < cnum; ++base) {
                int s0 = __shfl(sv, base);
                float ex0 = __shfl(av.x, base);
                float ey0 = __shfl(av.y, base);
                unsigned int k0 = A.kvb[(size_t)s0 * 64 + lane];
                edge(ex0, ey0, k0);
            }
        }

        float rden = 1.f / (den + 1e-16f);
        ax *= rden; ay *= rden;
        float2 xv = *(const float2*)&A.xrb[(size_t)n * 128 + ch];
        float gp = ax * wb_o.x + ay * wb_o.y + xv.x * wb_r.x + xv.y * wb_r.y
                 + (ax - xv.x) * wb_d.x + (ay - xv.y) * wb_d.y;
        gp += __shfl_xor(gp, 1);
        gp += __shfl_xor(gp, 2);
        gp += __shfl_xor(gp, 4);
        gp += __shfl_xor(gp, 8);
        gp += __shfl_xor(gp, 16);
        gp += __shfl_xor(gp, 32);
        float gate = 1.f / (1.f + __expf(-gp));
        float ox = gate * xv.x + (1.f - gate) * ax;
        float oy = gate * xv.y + (1.f - gate) * ay;
        *(float2*)&A.xbuf[(size_t)n * 128 + ch] = make_float2(ox, oy);
        bnsx += ox; bnsy += oy;
        bnqx = fmaf(ox, ox, bnqx); bnqy = fmaf(oy, oy, bnqy);
    }
    // block-level BN partial reduce (ss = s_sum[2][256] then s_sq[2][256])
    __syncthreads();
    float* s_sum0 = ss; float* s_sum1 = ss + 256;
    float* s_sq0 = ss + 512; float* s_sq1 = ss + 768;
    s_sum0[t] = bnsx; s_sum1[t] = bnsy;
    s_sq0[t] = bnqx;  s_sq1[t] = bnqy;
    __syncthreads();
    if (t < 64) {
        float sx = s_sum0[t] + s_sum0[64 + t] + s_sum0[128 + t] + s_sum0[192 + t];
        float sy = s_sum1[t] + s_sum1[64 + t] + s_sum1[128 + t] + s_sum1[192 + t];
        float qx = s_sq0[t] + s_sq0[64 + t] + s_sq0[128 + t] + s_sq0[192 + t];
        float qy = s_sq1[t] + s_sq1[64 + t] + s_sq1[128 + t] + s_sq1[192 + t];
        int c = 2 * t;
        atomicAdd(&bn_accum[c], sx);
        atomicAdd(&bn_accum[c + 1], sy);
        atomicAdd(&bn_accum[128 + c], qx);
        atomicAdd(&bn_accum[128 + c + 1], qy);
    }
}

// POOL phase: BN affine+ELU+dot(Wout), per-graph LDS accumulate, one flush per block.
__device__ __forceinline__ void pool_phase(const MegaArgs& A, float* lsum, int* lcnt,
                                           float* ab_s, int bid, int gstride) {
    int t = threadIdx.x;
    int lane = t & 63, wid = t >> 6;
    const float* bn_acc = A.bn_acc3 + 2 * 256;
    if (t < NGRAPH) { lsum[t] = 0.f; lcnt[t] = 0; }
    compute_ab(bn_acc, A.gamma + 2 * 128, A.beta + 2 * 128, ab_s, t);
    __syncthreads();
    int ch = lane * 2;
    float2 wo = *(const float2*)&A.Wout[ch];
    float2 a = *(const float2*)&ab_s[ch];
    float2 b = *(const float2*)&ab_s[128 + ch];
    for (int chunk = bid; chunk < (NN + 15) / 16; chunk += gstride) {
        int base = chunk * 16 + wid * 4;
#pragma unroll
        for (int i = 0; i < 4; i++) {
            int n = base + i;
            if (n < NN) {
                float2 xv = *(const float2*)&A.xbuf[(size_t)n * 128 + ch];
                float z0 = fmaf(xv.x, a.x, b.x); z0 = z0 > 0.f ? z0 : expm1f(z0);
                float z1 = fmaf(xv.y, a.y, b.y); z1 = z1 > 0.f ? z1 : expm1f(z1);
                float p = z0 * wo.x + z1 * wo.y;
                p += __shfl_xor(p, 1);
                p += __shfl_xor(p, 2);
                p += __shfl_xor(p, 4);
                p += __shfl_xor(p, 8);
                p += __shfl_xor(p, 16);
                p += __shfl_xor(p, 32);
                if (lane == 0) {
                    int g = A.batch[n];
                    atomicAdd(&lsum[g], p);
                    atomicAdd(&lcnt[g], 1);
                }
            }
        }
    }
    __syncthreads();
    if (t < NGRAPH && lcnt[t] > 0) {
        atomicAdd(&A.gsum[t], lsum[t]);
        atomicAdd(&A.gcnt[t], lcnt[t]);
    }
}

// ---------------- standalone kernels (fallback path) ----------------
__global__ __launch_bounds__(256) void k_gemm4s(MegaArgs A, int l) {
    __shared__ _Float16 xs[64][136];
    __shared__ float ab_s[256];
    int use_ab = (l != 0);
    if (use_ab) {
        compute_ab(A.bn_acc3 + (l - 1) * 256, A.gamma + (l - 1) * 128,
                   A.beta + (l - 1) * 128, ab_s, threadIdx.x);
        __syncthreads();
    }
    gemm_phase(A, l, xs, ab_s, use_ab, blockIdx.x, gridDim.x);
}

__global__ __launch_bounds__(256) void k_attns(MegaArgs A, int l) {
    __shared__ float ss[4 * 256];
    attn_phase(A, l, ss, blockIdx.x, gridDim.x);
}

__global__ __launch_bounds__(256) void k_pools(MegaArgs A) {
    __shared__ float lsum[64];
    __shared__ int lcnt[64];
    __shared__ float ab_s[256];
    pool_phase(A, lsum, lcnt, ab_s, blockIdx.x, gridDim.x);
}

__global__ void k_finals(MegaArgs A) {
    int g = threadIdx.x;
    if (g < NGRAPH) A.out[g] = A.gsum[g] / fmaxf((float)A.gcnt[g], 1.f) + A.bout[0] + A.obias[0];
}

// ---------------- mega-kernel (cooperative path) ----------------
union SharedU {
    struct { _Float16 xs[64][136]; float ab[256]; } g;
    struct { float ss[4 * 256]; } a;
    struct { float lsum[64]; int lcnt[64]; float ab[256]; } p;
};

__global__ void __launch_bounds__(256, 4) k_mega(MegaArgs A) {
    cg::grid_group grid = cg::this_grid();
    __shared__ SharedU sh;
    int t = threadIdx.x;
    for (int l = 0; l < 3; ++l) {
        int use_ab = (l != 0);
        if (use_ab) {
            compute_ab(A.bn_acc3 + (l - 1) * 256, A.gamma + (l - 1) * 128,
                       A.beta + (l - 1) * 128, sh.g.ab, t);
            __syncthreads();
        }
        gemm_phase(A, l, sh.g.xs, sh.g.ab, use_ab, blockIdx.x, gridDim.x);
        grid.sync();
        attn_phase(A, l, sh.a.ss, blockIdx.x, gridDim.x);
        grid.sync();
    }
    pool_phase(A, sh.p.lsum, sh.p.lcnt, sh.p.ab, blockIdx.x, gridDim.x);
    grid.sync();
    if (blockIdx.x == 0 && t < NGRAPH) {
        A.out[t] = A.gsum[t] / fmaxf((float)A.gcnt[t], 1.f) + A.bout[0] + A.obias[0];
    }
}

extern "C" void kernel_launch(void* const* d_in, const int* in_sizes, int n_in,
                              void* d_out, int out_size, void* d_ws, size_t ws_size,
                              hipStream_t stream) {
    const float* x_in       = (const float*)d_in[0];
    const int* eidx         = (const int*)d_in[1];
    const float* eattr      = (const float*)d_in[2];
    const int* batch        = (const int*)d_in[3];
    const float* Wq         = (const float*)d_in[4];
    const float* bq         = (const float*)d_in[5];
    const float* Wk         = (const float*)d_in[6];
    const float* bk         = (const float*)d_in[7];
    const float* Wv         = (const float*)d_in[8];
    const float* bv         = (const float*)d_in[9];
    const float* We         = (const float*)d_in[10];
    const float* be         = (const float*)d_in[11];
    const float* Wskip      = (const float*)d_in[12];
    const float* bskip      = (const float*)d_in[13];
    const float* Wbeta      = (const float*)d_in[14];
    const float* bn_gamma   = (const float*)d_in[15];
    const float* bn_beta    = (const float*)d_in[16];
    const float* Wout       = (const float*)d_in[17];
    const float* bout       = (const float*)d_in[18];
    const float* obias      = (const float*)d_in[19];
    float* out = (float*)d_out;

    char* ws = (char*)d_ws;
    size_t off = 0;
    auto alloc = [&](size_t bytes) -> void* {
        off = (off + 255) & ~(size_t)255;
        void* p = ws + off;
        off += bytes;
        return p;
    };
    const size_t NF = (size_t)NN * 128 * sizeof(float);
    float* xbuf    = (float*)alloc(NF);
    float* qb      = (float*)alloc(NF);
    float* xrb     = (float*)alloc(NF);
    unsigned int* kvb = (unsigned int*)alloc((size_t)NN * 64 * sizeof(unsigned int));
    _Float16* wt   = (_Float16*)alloc((size_t)12 * 16384 * sizeof(_Float16));
    int* row_ptr   = (int*)alloc((NN + 1) * sizeof(int));
    int* cnt       = (int*)alloc(NN * sizeof(int));
    int* esrc      = (int*)alloc(EE * sizeof(int));
    float* eat2    = (float*)alloc((size_t)EE * 2 * sizeof(float));
    float* bn_acc3 = (float*)alloc(3 * 256 * sizeof(float));
    float* gsum    = (float*)alloc(64 * sizeof(float));
    int* gcnt      = (int*)alloc(64 * sizeof(int));
    (void)ws_size; (void)n_in; (void)in_sizes; (void)out_size;

    // ---- CSR build + zero aux buffers + weight prep ----
    hipMemsetAsync(cnt, 0, NN * sizeof(int), stream);
    k_degprep<<<3125 + 768, 256, 0, stream>>>(eidx, cnt, Wq, Wk, Wv, Wskip, wt);
    k_scan<<<1, 1024, 0, stream>>>(cnt, row_ptr, bn_acc3, gsum, gcnt);
    k_scatter<<<(EE + 255) / 256, 256, 0, stream>>>(eidx, eattr, row_ptr, cnt, esrc, eat2);

    MegaArgs A;
    A.x_in = x_in; A.wt = wt;
    A.bq = bq; A.bk = bk; A.bv = bv; A.bs = bskip;
    A.We = We; A.be = be; A.Wb = Wbeta;
    A.gamma = bn_gamma; A.beta = bn_beta;
    A.Wout = Wout; A.bout = bout; A.obias = obias;
    A.esrc = esrc; A.eat2 = eat2; A.row_ptr = row_ptr; A.batch = batch;
    A.qb = qb; A.kvb = kvb; A.xrb = xrb; A.xbuf = xbuf;
    A.bn_acc3 = bn_acc3; A.gsum = gsum; A.gcnt = gcnt; A.out = out;

    void* kargs[] = { &A };
    hipError_t st = hipLaunchCooperativeKernel((const void*)k_mega, dim3(MEGA_BLOCKS),
                                               dim3(256), kargs, 0, stream);
    if (st != hipSuccess) {
        (void)hipGetLastError();   // clear sticky error, fall back to 8-launch pipeline
        for (int l = 0; l < 3; ++l) {
            k_gemm4s<<<GEMM_TILES, 256, 0, stream>>>(A, l);
            k_attns<<<3125, 256, 0, stream>>>(A, l);
        }
        k_pools<<<(NN + 15) / 16, 256, 0, stream>>>(A);
        k_finals<<<1, 64, 0, stream>>>(A);
    }
}

// Round 14
// 1041.677 us; speedup vs baseline: 1.8204x; 1.8204x over previous
//
#include <hip/hip_runtime.h>
#include <hip/hip_fp16.h>
#include <math.h>

#define NN 50000
#define EE 800000
#define HIDDEN 128
#define NGRAPH 50

typedef _Float16 half8 __attribute__((ext_vector_type(8)));
typedef float f32x4 __attribute__((ext_vector_type(4)));

// ---------------- CSR degree count + weight transpose (union grid) ----------------
__global__ void k_degprep(const int* __restrict__ eidx, int* __restrict__ cnt,
                          const float* __restrict__ Wq, const float* __restrict__ Wk,
                          const float* __restrict__ Wv, const float* __restrict__ Ws,
                          _Float16* __restrict__ wt) {
    int b = blockIdx.x;
    int t = threadIdx.x;
    if (b < 3125) {
        int e = b * 256 + t;
        if (e < EE) atomicAdd(&cnt[eidx[EE + e]], 1);
    } else {
        int idx = (b - 3125) * 256 + t;   // 12 * 16384 fp16 transposed weights
        if (idx < 12 * 16384) {
            int mat = idx >> 14;
            int l = mat >> 2, w = mat & 3;
            int nk = idx & 16383;
            int n = nk >> 7, k = nk & 127;
            const float* W = (w == 0 ? Wq : w == 1 ? Wk : w == 2 ? Wv : Ws) + (size_t)l * 16384;
            wt[idx] = (_Float16)W[k * 128 + n];
        }
    }
}

// scan + housekeeping: exclusive-scan deg->row_ptr (4 elems/thread), zero cnt,
// zero bn_acc3 / gsum / gcnt
__global__ void k_scan(int* __restrict__ cnt, int* __restrict__ row_ptr,
                       float* __restrict__ bn_acc3, float* __restrict__ gsum,
                       int* __restrict__ gcnt) {
    __shared__ int wsum[16];
    __shared__ int carry_s;
    int t = threadIdx.x;
    int lane = t & 63, w = t >> 6;
    if (t < 768) bn_acc3[t] = 0.f;
    if (t < 64) { gsum[t] = 0.f; gcnt[t] = 0; }
    if (t == 0) carry_s = 0;
    __syncthreads();
    for (int base = 0; base < NN; base += 4096) {
        int i0 = base + t * 4;
        int v[4];
#pragma unroll
        for (int j = 0; j < 4; j++) v[j] = (i0 + j < NN) ? cnt[i0 + j] : 0;
        int s4 = v[0] + v[1] + v[2] + v[3];
        int s = s4;
#pragma unroll
        for (int o = 1; o < 64; o <<= 1) {
            int u = __shfl_up(s, o);
            if (lane >= o) s += u;
        }
        if (lane == 63) wsum[w] = s;
        __syncthreads();
        if (w == 0) {
            int ws = (lane < 16) ? wsum[lane] : 0;
#pragma unroll
            for (int o = 1; o < 16; o <<= 1) {
                int u = __shfl_up(ws, o);
                if (lane >= o) ws += u;
            }
            if (lane < 16) wsum[lane] = ws;
        }
        __syncthreads();
        int wpre = (w == 0) ? 0 : wsum[w - 1];
        int run = carry_s + wpre + s - s4;
#pragma unroll
        for (int j = 0; j < 4; j++) {
            if (i0 + j < NN) { row_ptr[i0 + j] = run; cnt[i0 + j] = 0; run += v[j]; }
        }
        __syncthreads();
        if (t == 0) carry_s += wsum[15];
        __syncthreads();
    }
    if (t == 0) row_ptr[NN] = carry_s;
}

// scatter: build CSR-ordered src-index and edge-attr arrays
__global__ void k_scatter(const int* __restrict__ eidx, const float* __restrict__ eattr,
                          const int* __restrict__ row_ptr,
                          int* __restrict__ cur, int* __restrict__ esrc, float* __restrict__ eat2) {
    int e = blockIdx.x * blockDim.x + threadIdx.x;
    if (e < EE) {
        int d = eidx[EE + e];
        int s = eidx[e];
        int p = atomicAdd(&cur[d], 1);
        int pos = row_ptr[d] + p;
        esrc[pos] = s;
        float2 ea = *(const float2*)&eattr[2 * (size_t)e];
        *(float2*)&eat2[2 * (size_t)pos] = ea;
    }
}

// ---- fused 4-way GEMM via f16 MFMA: q,xr fp32 out; k,v packed OCP fp8 e4m3.
// When use_ab: BN affine+ELU applied to input X (stats from bn_acc) during staging.
__global__ __launch_bounds__(256) void k_gemm4(
    const float* __restrict__ X, const _Float16* __restrict__ wt,
    const float* __restrict__ bq, const float* __restrict__ bk,
    const float* __restrict__ bv, const float* __restrict__ bs,
    const float* __restrict__ bn_acc, const float* __restrict__ gamma,
    const float* __restrict__ beta, int use_ab,
    float* __restrict__ qo, unsigned int* __restrict__ kvb, float* __restrict__ xro)
{
    __shared__ _Float16 xs[64][136];
    __shared__ float ab_s[256];
    int t = threadIdx.x;
    int m0 = blockIdx.x * 64;
    if (use_ab) {
        if (t < 128) {
            float mu = bn_acc[t] * (1.f / NN);
            float var = bn_acc[128 + t] * (1.f / NN) - mu * mu;
            float inv = rsqrtf(var + 1e-5f);
            float a = inv * gamma[t];
            ab_s[t] = a;
            ab_s[128 + t] = beta[t] - mu * a;
        }
        __syncthreads();
    }
#pragma unroll
    for (int i = 0; i < 8; ++i) {
        int f = t + 256 * i;          // float4 index within 64x32
        int r = f >> 5, c4 = (f & 31) << 2;
        float4 val = make_float4(0.f, 0.f, 0.f, 0.f);
        if (m0 + r < NN) val = *(const float4*)&X[(size_t)(m0 + r) * 128 + c4];
        if (use_ab) {
            float4 a = *(const float4*)&ab_s[c4];
            float4 bb = *(const float4*)&ab_s[128 + c4];
            float z;
            z = fmaf(val.x, a.x, bb.x); val.x = z > 0.f ? z : expm1f(z);
            z = fmaf(val.y, a.y, bb.y); val.y = z > 0.f ? z : expm1f(z);
            z = fmaf(val.z, a.z, bb.z); val.z = z > 0.f ? z : expm1f(z);
            z = fmaf(val.w, a.w, bb.w); val.w = z > 0.f ? z : expm1f(z);
        }
        _Float16* dst = &xs[r][c4];
        dst[0] = (_Float16)val.x; dst[1] = (_Float16)val.y;
        dst[2] = (_Float16)val.z; dst[3] = (_Float16)val.w;
    }
    __syncthreads();
    int lane = t & 63, wid = t >> 6;
    int quad = lane >> 4, l15 = lane & 15;
    int mrow = wid * 16;
    half8 afrag[4];
#pragma unroll
    for (int kk = 0; kk < 4; kk++)
        afrag[kk] = *(const half8*)&xs[mrow + l15][kk * 32 + quad * 8];

#pragma unroll
    for (int nt = 0; nt < 8; nt++) {
        int c = nt * 16 + l15;
        f32x4 acc[4];
#pragma unroll
        for (int w = 0; w < 4; w++) acc[w] = (f32x4){0.f, 0.f, 0.f, 0.f};
#pragma unroll
        for (int kk = 0; kk < 4; kk++) {
            half8 bf[4];
#pragma unroll
            for (int w = 0; w < 4; w++)
                bf[w] = *(const half8*)&wt[(size_t)w * 16384 + c * 128 + kk * 32 + quad * 8];
#pragma unroll
            for (int w = 0; w < 4; w++)
                acc[w] = __builtin_amdgcn_mfma_f32_16x16x32_f16(afrag[kk], bf[w], acc[w], 0, 0, 0);
        }
        float bqv = bq[c], bkv = bk[c], bvv = bv[c], bsv = bs[c];
        int nodebase = m0 + mrow + quad * 4;
#pragma unroll
        for (int r = 0; r < 4; r++) {
            int node = nodebase + r;
            bool ok = node < NN;
            float qv = acc[0][r] + bqv;
            float xv = acc[3][r] + bsv;
            float kf = acc[1][r] + bkv;
            float vf = acc[2][r] + bvv;
            float kf1 = __shfl_xor(kf, 1);
            float vf1 = __shfl_xor(vf, 1);
            if (ok) {
                qo[(size_t)node * 128 + c] = qv;
                xro[(size_t)node * 128 + c] = xv;
                if (!(lane & 1)) {
                    // pack {k[c],k[c+1],v[c],v[c+1]} as 4x fp8 e4m3 in one word
                    int w2 = __builtin_amdgcn_cvt_pk_fp8_f32(kf, kf1, 0, false);
                    w2 = __builtin_amdgcn_cvt_pk_fp8_f32(vf, vf1, w2, true);
                    kvb[(size_t)node * 64 + (c >> 1)] = (unsigned int)w2;
                }
            }
        }
    }
}

// ---------------- attention + gate + BN-stats (one wave per dst node) ----------------
// Gather via global_load_lds direct-to-LDS DMA: per 16-edge group, 4 dwordx4
// instructions (lanes 0-15 -> row j, 16-31 -> j+1, ...), one vmcnt(0), consume
// from LDS. 16 rows (64 lines) in flight per wave with zero gather VGPRs.
__global__ __launch_bounds__(256) void k_attn(
    const float* __restrict__ q, const unsigned int* __restrict__ kvb,
    const float* __restrict__ xr,
    const int* __restrict__ esrc, const float* __restrict__ eat2,
    const int* __restrict__ row_ptr,
    const float* __restrict__ We, const float* __restrict__ be,
    const float* __restrict__ Wb,
    float* __restrict__ out2, float* __restrict__ bn_accum)
{
    __shared__ unsigned int shkv[4][16][64];   // 16 KB: per-wave 16 kv rows
    int t = threadIdx.x;
    int lane = t & 63;
    int wid = t >> 6;
    int gwave = blockIdx.x * 4 + wid;
    int nwaves = gridDim.x * 4;
    int ch = lane * 2;
    int sub = lane >> 4;        // which of 4 rows this lane's 16-B chunk feeds
    int l16 = lane & 15;
    float2 we0 = *(const float2*)&We[ch];
    float2 we1 = *(const float2*)&We[128 + ch];
    float2 beL = *(const float2*)&be[ch];
    float2 wb_o = *(const float2*)&Wb[ch];
    float2 wb_r = *(const float2*)&Wb[128 + ch];
    float2 wb_d = *(const float2*)&Wb[256 + ch];
    const float scale = 0.17677669529663687f;   // 1/sqrt(32)
    float bnsx = 0.f, bnsy = 0.f, bnqx = 0.f, bnqy = 0.f;

    for (int n = gwave; n < NN; n += nwaves) {
        int rs = __builtin_amdgcn_readfirstlane(row_ptr[n]);
        int re = __builtin_amdgcn_readfirstlane(row_ptr[n + 1]);
        float2 qv = *(const float2*)&q[(size_t)n * 128 + ch];
        float den = 0.f;
        float ax = 0.f, ay = 0.f;

        for (int cb = rs; cb < re; cb += 64) {
            int cnum = re - cb; if (cnum > 64) cnum = 64;
            int mi = cb + lane;
            int sv = 0;                          // invalid lanes -> row 0 (hot, masked)
            float2 av = make_float2(0.f, 0.f);
            if (mi < re) {
                sv = esrc[mi];
                av = *(const float2*)&eat2[2 * (size_t)mi];
            }
            for (int base = 0; base < cnum; base += 16) {
                // issue 4 direct-to-LDS dwordx4 loads covering edges base..base+15
#pragma unroll
                for (int ii = 0; ii < 4; ii++) {
                    int src = __shfl(sv, base + 4 * ii + sub);
                    const unsigned int* gp = kvb + (size_t)src * 64 + l16 * 4;
                    __builtin_amdgcn_global_load_lds(
                        (const __attribute__((address_space(1))) unsigned int*)gp,
                        (__attribute__((address_space(3))) unsigned int*)&shkv[wid][4 * ii][0],
                        16, 0, 0);
                }
                __builtin_amdgcn_s_waitcnt(0x0F70);   // vmcnt(0)
                __asm__ __volatile__("" ::: "memory");
                int m = cnum - base; if (m > 16) m = 16;
#pragma unroll
                for (int j = 0; j < 16; j++) {
                    unsigned int w8 = shkv[wid][j][lane];
                    float eax = __shfl(av.x, base + j);
                    float eay = __shfl(av.y, base + j);
                    auto kf = __builtin_amdgcn_cvt_pk_f32_fp8((int)w8, false);
                    auto vf = __builtin_amdgcn_cvt_pk_f32_fp8((int)w8, true);
                    float ex_ = fmaf(eax, we0.x, fmaf(eay, we1.x, beL.x));
                    float ey_ = fmaf(eax, we0.y, fmaf(eay, we1.y, beL.y));
                    float p = qv.x * (kf[0] + ex_) + qv.y * (kf[1] + ey_);
                    p += __shfl_xor(p, 1);
                    p += __shfl_xor(p, 2);
                    p += __shfl_xor(p, 4);
                    p += __shfl_xor(p, 8);
                    float alpha = (j < m) ? p * scale : -1.0e30f;
                    float exv = __expf(alpha);
                    den += exv;
                    ax = fmaf(exv, vf[0] + ex_, ax);
                    ay = fmaf(exv, vf[1] + ey_, ay);
                }
            }
        }

        float rden = 1.f / (den + 1e-16f);
        ax *= rden; ay *= rden;
        // beta gate
        float2 xv = *(const float2*)&xr[(size_t)n * 128 + ch];
        float gp = ax * wb_o.x + ay * wb_o.y + xv.x * wb_r.x + xv.y * wb_r.y
                 + (ax - xv.x) * wb_d.x + (ay - xv.y) * wb_d.y;
        gp += __shfl_xor(gp, 1);
        gp += __shfl_xor(gp, 2);
        gp += __shfl_xor(gp, 4);
        gp += __shfl_xor(gp, 8);
        gp += __shfl_xor(gp, 16);
        gp += __shfl_xor(gp, 32);
        float gate = 1.f / (1.f + __expf(-gp));
        float ox = gate * xv.x + (1.f - gate) * ax;
        float oy = gate * xv.y + (1.f - gate) * ay;
        *(float2*)&out2[(size_t)n * 128 + ch] = make_float2(ox, oy);
        bnsx += ox; bnsy += oy;
        bnqx = fmaf(ox, ox, bnqx); bnqy = fmaf(oy, oy, bnqy);
    }
    // block-level BN partial reduce
    __shared__ float s_sum[2][256], s_sq[2][256];
    __syncthreads();
    s_sum[0][t] = bnsx; s_sum[1][t] = bnsy;
    s_sq[0][t] = bnqx;  s_sq[1][t] = bnqy;
    __syncthreads();
    if (t < 64) {
        float sx = s_sum[0][t] + s_sum[0][64 + t] + s_sum[0][128 + t] + s_sum[0][192 + t];
        float sy = s_sum[1][t] + s_sum[1][64 + t] + s_sum[1][128 + t] + s_sum[1][192 + t];
        float qx = s_sq[0][t] + s_sq[0][64 + t] + s_sq[0][128 + t] + s_sq[0][192 + t];
        float qy = s_sq[1][t] + s_sq[1][64 + t] + s_sq[1][128 + t] + s_sq[1][192 + t];
        int c = 2 * t;
        atomicAdd(&bn_accum[c], sx);
        atomicAdd(&bn_accum[c + 1], sy);
        atomicAdd(&bn_accum[128 + c], qx);
        atomicAdd(&bn_accum[128 + c + 1], qy);
    }
}

// ------- readout: BN affine+ELU+dot(Wout), LDS per-graph accumulate, one flush per block -------
__global__ __launch_bounds__(256) void k_pool(const float* __restrict__ x,
                                              const float* __restrict__ bn_acc,
                                              const float* __restrict__ gamma,
                                              const float* __restrict__ beta,
                                              const float* __restrict__ Wout,
                                              const int* __restrict__ batch,
                                              float* __restrict__ gsum, int* __restrict__ gcnt) {
    __shared__ float lsum[NGRAPH];
    __shared__ int lcnt[NGRAPH];
    __shared__ float ab_s[256];
    int t = threadIdx.x;
    if (t < NGRAPH) { lsum[t] = 0.f; lcnt[t] = 0; }
    if (t < 128) {
        float mu = bn_acc[t] * (1.f / NN);
        float var = bn_acc[128 + t] * (1.f / NN) - mu * mu;
        float inv = rsqrtf(var + 1e-5f);
        float a = inv * gamma[t];
        ab_s[t] = a;
        ab_s[128 + t] = beta[t] - mu * a;
    }
    __syncthreads();
    int lane = t & 63;
    int wid = t >> 6;
    int ch = lane * 2;
    float2 wo = *(const float2*)&Wout[ch];
    float2 a = *(const float2*)&ab_s[ch];
    float2 b = *(const float2*)&ab_s[128 + ch];
    int base = blockIdx.x * 16 + wid * 4;
#pragma unroll
    for (int i = 0; i < 4; i++) {
        int n = base + i;
        if (n < NN) {
            float2 xv = *(const float2*)&x[(size_t)n * 128 + ch];
            float z0 = fmaf(xv.x, a.x, b.x); z0 = z0 > 0.f ? z0 : expm1f(z0);
            float z1 = fmaf(xv.y, a.y, b.y); z1 = z1 > 0.f ? z1 : expm1f(z1);
            float p = z0 * wo.x + z1 * wo.y;
            p += __shfl_xor(p, 1);
            p += __shfl_xor(p, 2);
            p += __shfl_xor(p, 4);
            p += __shfl_xor(p, 8);
            p += __shfl_xor(p, 16);
            p += __shfl_xor(p, 32);
            if (lane == 0) {
                int g = batch[n];
                atomicAdd(&lsum[g], p);
                atomicAdd(&lcnt[g], 1);
            }
        }
    }
    __syncthreads();
    if (t < NGRAPH && lcnt[t] > 0) {
        atomicAdd(&gsum[t], lsum[t]);
        atomicAdd(&gcnt[t], lcnt[t]);
    }
}

__global__ void k_final(const float* __restrict__ gsum, const int* __restrict__ gcnt,
                        const float* __restrict__ bout, const float* __restrict__ obias,
                        float* __restrict__ out) {
    int g = threadIdx.x;
    if (g < NGRAPH) out[g] = gsum[g] / fmaxf((float)gcnt[g], 1.f) + bout[0] + obias[0];
}

extern "C" void kernel_launch(void* const* d_in, const int* in_sizes, int n_in,
                              void* d_out, int out_size, void* d_ws, size_t ws_size,
                              hipStream_t stream) {
    const float* x_in       = (const float*)d_in[0];
    const int* eidx         = (const int*)d_in[1];
    const float* eattr      = (const float*)d_in[2];
    const int* batch        = (const int*)d_in[3];
    const float* Wq         = (const float*)d_in[4];
    const float* bq         = (const float*)d_in[5];
    const float* Wk         = (const float*)d_in[6];
    const float* bk         = (const float*)d_in[7];
    const float* Wv         = (const float*)d_in[8];
    const float* bv         = (const float*)d_in[9];
    const float* We         = (const float*)d_in[10];
    const float* be         = (const float*)d_in[11];
    const float* Wskip      = (const float*)d_in[12];
    const float* bskip      = (const float*)d_in[13];
    const float* Wbeta      = (const float*)d_in[14];
    const float* bn_gamma   = (const float*)d_in[15];
    const float* bn_beta    = (const float*)d_in[16];
    const float* Wout       = (const float*)d_in[17];
    const float* bout       = (const float*)d_in[18];
    const float* obias      = (const float*)d_in[19];
    float* out = (float*)d_out;

    char* ws = (char*)d_ws;
    size_t off = 0;
    auto alloc = [&](size_t bytes) -> void* {
        off = (off + 255) & ~(size_t)255;
        void* p = ws + off;
        off += bytes;
        return p;
    };
    const size_t NF = (size_t)NN * 128 * sizeof(float);
    float* xbuf    = (float*)alloc(NF);
    float* qb      = (float*)alloc(NF);
    float* xrb     = (float*)alloc(NF);
    unsigned int* kvb = (unsigned int*)alloc((size_t)NN * 64 * sizeof(unsigned int));
    _Float16* wt   = (_Float16*)alloc((size_t)12 * 16384 * sizeof(_Float16));
    int* row_ptr   = (int*)alloc((NN + 1) * sizeof(int));
    int* cnt       = (int*)alloc(NN * sizeof(int));
    int* esrc      = (int*)alloc(EE * sizeof(int));
    float* eat2    = (float*)alloc((size_t)EE * 2 * sizeof(float));
    float* bn_acc3 = (float*)alloc(3 * 256 * sizeof(float));
    float* gsum    = (float*)alloc(64 * sizeof(float));
    int* gcnt      = (int*)alloc(64 * sizeof(int));
    (void)ws_size; (void)n_in; (void)in_sizes; (void)out_size;

    // ---- CSR build (dst -> src, eattr reordered) + zero aux buffers + weight prep ----
    hipMemsetAsync(cnt, 0, NN * sizeof(int), stream);
    k_degprep<<<3125 + 768, 256, 0, stream>>>(eidx, cnt, Wq, Wk, Wv, Wskip, wt);
    k_scan<<<1, 1024, 0, stream>>>(cnt, row_ptr, bn_acc3, gsum, gcnt);
    k_scatter<<<(EE + 255) / 256, 256, 0, stream>>>(eidx, eattr, row_ptr, cnt, esrc, eat2);

    // ---- layers ----
    for (int l = 0; l < 3; ++l) {
        const float* Xl = (l == 0) ? x_in : xbuf;
        const float* prev_acc = (l == 0) ? bn_acc3 : bn_acc3 + (l - 1) * 256;
        k_gemm4<<<(NN + 63) / 64, 256, 0, stream>>>(
            Xl, wt + (size_t)l * 65536,
            bq + l * 128, bk + l * 128, bv + l * 128, bskip + l * 128,
            prev_acc, bn_gamma + (l == 0 ? 0 : (l - 1) * 128),
            bn_beta + (l == 0 ? 0 : (l - 1) * 128), (l == 0) ? 0 : 1,
            qb, kvb, xrb);
        k_attn<<<3125, 256, 0, stream>>>(
            qb, kvb, xrb, esrc, eat2, row_ptr,
            We + (size_t)l * 256, be + l * 128, Wbeta + (size_t)l * 384,
            xbuf, bn_acc3 + l * 256);
    }

    // ---- readout (BN affine+ELU of layer-2 fused in) ----
    k_pool<<<(NN + 15) / 16, 256, 0, stream>>>(xbuf, bn_acc3 + 2 * 256,
                                               bn_gamma + 2 * 128, bn_beta + 2 * 128,
                                               Wout, batch, gsum, gcnt);
    k_final<<<1, 64, 0, stream>>>(gsum, gcnt, bout, obias, out);
}

// Round 15
// 992.000 us; speedup vs baseline: 1.9116x; 1.0501x over previous
//
#include <hip/hip_runtime.h>
#include <hip/hip_fp16.h>
#include <math.h>

#define NN 50000
#define EE 800000
#define HIDDEN 128
#define NGRAPH 50
#define GEMM_TILES ((NN + 63) / 64)

typedef _Float16 half8 __attribute__((ext_vector_type(8)));
typedef float f32x4 __attribute__((ext_vector_type(4)));

// ---------------- CSR degree count + weight transpose (union grid) ----------------
__global__ void k_degprep(const int* __restrict__ eidx, int* __restrict__ cnt,
                          const float* __restrict__ Wq, const float* __restrict__ Wk,
                          const float* __restrict__ Wv, const float* __restrict__ Ws,
                          _Float16* __restrict__ wt) {
    int b = blockIdx.x;
    int t = threadIdx.x;
    if (b < 3125) {
        int e = b * 256 + t;
        if (e < EE) atomicAdd(&cnt[eidx[EE + e]], 1);
    } else {
        int idx = (b - 3125) * 256 + t;   // 12 * 16384 fp16 transposed weights
        if (idx < 12 * 16384) {
            int mat = idx >> 14;
            int l = mat >> 2, w = mat & 3;
            int nk = idx & 16383;
            int n = nk >> 7, k = nk & 127;
            const float* W = (w == 0 ? Wq : w == 1 ? Wk : w == 2 ? Wv : Ws) + (size_t)l * 16384;
            wt[idx] = (_Float16)W[k * 128 + n];
        }
    }
}

// scan + housekeeping: exclusive-scan deg->row_ptr (4 elems/thread), zero cnt,
// zero bn_acc3 / gsum / gcnt
__global__ void k_scan(int* __restrict__ cnt, int* __restrict__ row_ptr,
                       float* __restrict__ bn_acc3, float* __restrict__ gsum,
                       int* __restrict__ gcnt) {
    __shared__ int wsum[16];
    __shared__ int carry_s;
    int t = threadIdx.x;
    int lane = t & 63, w = t >> 6;
    if (t < 768) bn_acc3[t] = 0.f;
    if (t < 64) { gsum[t] = 0.f; gcnt[t] = 0; }
    if (t == 0) carry_s = 0;
    __syncthreads();
    for (int base = 0; base < NN; base += 4096) {
        int i0 = base + t * 4;
        int v[4];
#pragma unroll
        for (int j = 0; j < 4; j++) v[j] = (i0 + j < NN) ? cnt[i0 + j] : 0;
        int s4 = v[0] + v[1] + v[2] + v[3];
        int s = s4;
#pragma unroll
        for (int o = 1; o < 64; o <<= 1) {
            int u = __shfl_up(s, o);
            if (lane >= o) s += u;
        }
        if (lane == 63) wsum[w] = s;
        __syncthreads();
        if (w == 0) {
            int ws = (lane < 16) ? wsum[lane] : 0;
#pragma unroll
            for (int o = 1; o < 16; o <<= 1) {
                int u = __shfl_up(ws, o);
                if (lane >= o) ws += u;
            }
            if (lane < 16) wsum[lane] = ws;
        }
        __syncthreads();
        int wpre = (w == 0) ? 0 : wsum[w - 1];
        int run = carry_s + wpre + s - s4;
#pragma unroll
        for (int j = 0; j < 4; j++) {
            if (i0 + j < NN) { row_ptr[i0 + j] = run; cnt[i0 + j] = 0; run += v[j]; }
        }
        __syncthreads();
        if (t == 0) carry_s += wsum[15];
        __syncthreads();
    }
    if (t == 0) row_ptr[NN] = carry_s;
}

// ---- GEMM tile body via f16 MFMA: q,xr fp32 out; k,v packed OCP fp8 e4m3 ----
__device__ __forceinline__ void gemm_tile(
    const float* __restrict__ X, const _Float16* __restrict__ wt,
    const float* __restrict__ bq, const float* __restrict__ bk,
    const float* __restrict__ bv, const float* __restrict__ bs,
    const float* ab_s, int use_ab, _Float16 (*xs)[136],
    float* __restrict__ qo, unsigned int* __restrict__ kvb, float* __restrict__ xro,
    int m0)
{
    int t = threadIdx.x;
    int lane = t & 63, wid = t >> 6;
#pragma unroll
    for (int i = 0; i < 8; ++i) {
        int f = t + 256 * i;          // float4 index within 64x32
        int r = f >> 5, c4 = (f & 31) << 2;
        float4 val = make_float4(0.f, 0.f, 0.f, 0.f);
        if (m0 + r < NN) val = *(const float4*)&X[(size_t)(m0 + r) * 128 + c4];
        if (use_ab) {
            float4 a = *(const float4*)&ab_s[c4];
            float4 bb = *(const float4*)&ab_s[128 + c4];
            float z;
            z = fmaf(val.x, a.x, bb.x); val.x = z > 0.f ? z : expm1f(z);
            z = fmaf(val.y, a.y, bb.y); val.y = z > 0.f ? z : expm1f(z);
            z = fmaf(val.z, a.z, bb.z); val.z = z > 0.f ? z : expm1f(z);
            z = fmaf(val.w, a.w, bb.w); val.w = z > 0.f ? z : expm1f(z);
        }
        _Float16* dst = &xs[r][c4];
        dst[0] = (_Float16)val.x; dst[1] = (_Float16)val.y;
        dst[2] = (_Float16)val.z; dst[3] = (_Float16)val.w;
    }
    __syncthreads();
    int quad = lane >> 4, l15 = lane & 15;
    int mrow = wid * 16;
    half8 afrag[4];
#pragma unroll
    for (int kk = 0; kk < 4; kk++)
        afrag[kk] = *(const half8*)&xs[mrow + l15][kk * 32 + quad * 8];

#pragma unroll
    for (int nt = 0; nt < 8; nt++) {
        int c = nt * 16 + l15;
        f32x4 acc[4];
#pragma unroll
        for (int w = 0; w < 4; w++) acc[w] = (f32x4){0.f, 0.f, 0.f, 0.f};
#pragma unroll
        for (int kk = 0; kk < 4; kk++) {
            half8 bf[4];
#pragma unroll
            for (int w = 0; w < 4; w++)
                bf[w] = *(const half8*)&wt[(size_t)w * 16384 + c * 128 + kk * 32 + quad * 8];
#pragma unroll
            for (int w = 0; w < 4; w++)
                acc[w] = __builtin_amdgcn_mfma_f32_16x16x32_f16(afrag[kk], bf[w], acc[w], 0, 0, 0);
        }
        float bqv = bq[c], bkv = bk[c], bvv = bv[c], bsv = bs[c];
        int nodebase = m0 + mrow + quad * 4;
#pragma unroll
        for (int r = 0; r < 4; r++) {
            int node = nodebase + r;
            bool ok = node < NN;
            float qv = acc[0][r] + bqv;
            float xv = acc[3][r] + bsv;
            float kf = acc[1][r] + bkv;
            float vf = acc[2][r] + bvv;
            float kf1 = __shfl_xor(kf, 1);
            float vf1 = __shfl_xor(vf, 1);
            if (ok) {
                qo[(size_t)node * 128 + c] = qv;
                xro[(size_t)node * 128 + c] = xv;
                if (!(lane & 1)) {
                    int w2 = __builtin_amdgcn_cvt_pk_fp8_f32(kf, kf1, 0, false);
                    w2 = __builtin_amdgcn_cvt_pk_fp8_f32(vf, vf1, w2, true);
                    kvb[(size_t)node * 64 + (c >> 1)] = (unsigned int)w2;
                }
            }
        }
    }
}

// ---- layer-0 GEMM fused with CSR scatter (independent work, union grid) ----
__global__ __launch_bounds__(256) void k_gemm0scat(
    const float* __restrict__ X, const _Float16* __restrict__ wt,
    const float* __restrict__ bq, const float* __restrict__ bk,
    const float* __restrict__ bv, const float* __restrict__ bs,
    float* __restrict__ qo, unsigned int* __restrict__ kvb, float* __restrict__ xro,
    const int* __restrict__ eidx, const float* __restrict__ eattr,
    const int* __restrict__ row_ptr, int* __restrict__ cur,
    int* __restrict__ esrc, float* __restrict__ eat2)
{
    __shared__ _Float16 xs[64][136];
    int b = blockIdx.x;
    if (b < GEMM_TILES) {
        gemm_tile(X, wt, bq, bk, bv, bs, nullptr, 0, xs, qo, kvb, xro, b * 64);
    } else {
        int e = (b - GEMM_TILES) * 256 + threadIdx.x;
        if (e < EE) {
            int d = eidx[EE + e];
            int s = eidx[e];
            int p = atomicAdd(&cur[d], 1);
            int pos = row_ptr[d] + p;
            esrc[pos] = s;
            float2 ea = *(const float2*)&eattr[2 * (size_t)e];
            *(float2*)&eat2[2 * (size_t)pos] = ea;
        }
    }
}

// ---- layers 1,2 GEMM (BN affine+ELU on input from bn_acc stats) ----
__global__ __launch_bounds__(256) void k_gemm4(
    const float* __restrict__ X, const _Float16* __restrict__ wt,
    const float* __restrict__ bq, const float* __restrict__ bk,
    const float* __restrict__ bv, const float* __restrict__ bs,
    const float* __restrict__ bn_acc, const float* __restrict__ gamma,
    const float* __restrict__ beta,
    float* __restrict__ qo, unsigned int* __restrict__ kvb, float* __restrict__ xro)
{
    __shared__ _Float16 xs[64][136];
    __shared__ float ab_s[256];
    int t = threadIdx.x;
    if (t < 128) {
        float mu = bn_acc[t] * (1.f / NN);
        float var = bn_acc[128 + t] * (1.f / NN) - mu * mu;
        float inv = rsqrtf(var + 1e-5f);
        float a = inv * gamma[t];
        ab_s[t] = a;
        ab_s[128 + t] = beta[t] - mu * a;
    }
    __syncthreads();
    gemm_tile(X, wt, bq, bk, bv, bs, ab_s, 1, xs, qo, kvb, xro, blockIdx.x * 64);
}

// ---------------- attention + gate + BN-stats (one wave per dst node) ----------------
// r10-exact structure (best measured: 182us): cooperative lane-load of CSR src/attr,
// groups of 8 fp8 kv gathers in flight + scalar tail.
__global__ __launch_bounds__(256) void k_attn(
    const float* __restrict__ q, const unsigned int* __restrict__ kvb,
    const float* __restrict__ xr,
    const int* __restrict__ esrc, const float* __restrict__ eat2,
    const int* __restrict__ row_ptr,
    const float* __restrict__ We, const float* __restrict__ be,
    const float* __restrict__ Wb,
    float* __restrict__ out2, float* __restrict__ bn_accum)
{
    int t = threadIdx.x;
    int lane = t & 63;
    int wid = t >> 6;
    int gwave = blockIdx.x * 4 + wid;
    int nwaves = gridDim.x * 4;
    int ch = lane * 2;
    float2 we0 = *(const float2*)&We[ch];
    float2 we1 = *(const float2*)&We[128 + ch];
    float2 beL = *(const float2*)&be[ch];
    float2 wb_o = *(const float2*)&Wb[ch];
    float2 wb_r = *(const float2*)&Wb[128 + ch];
    float2 wb_d = *(const float2*)&Wb[256 + ch];
    const float scale = 0.17677669529663687f;   // 1/sqrt(32)
    float bnsx = 0.f, bnsy = 0.f, bnqx = 0.f, bnqy = 0.f;

    for (int n = gwave; n < NN; n += nwaves) {
        int rs = __builtin_amdgcn_readfirstlane(row_ptr[n]);
        int re = __builtin_amdgcn_readfirstlane(row_ptr[n + 1]);
        float2 qv = *(const float2*)&q[(size_t)n * 128 + ch];
        float den = 0.f;
        float ax = 0.f, ay = 0.f;

        auto edge = [&](float eax, float eay, unsigned int w8) {
            auto kf = __builtin_amdgcn_cvt_pk_f32_fp8((int)w8, false);
            auto vf = __builtin_amdgcn_cvt_pk_f32_fp8((int)w8, true);
            float ex_ = fmaf(eax, we0.x, fmaf(eay, we1.x, beL.x));
            float ey_ = fmaf(eax, we0.y, fmaf(eay, we1.y, beL.y));
            float p = qv.x * (kf[0] + ex_) + qv.y * (kf[1] + ey_);
            p += __shfl_xor(p, 1);
            p += __shfl_xor(p, 2);
            p += __shfl_xor(p, 4);
            p += __shfl_xor(p, 8);
            float exv = __expf(p * scale);
            den += exv;
            ax = fmaf(exv, vf[0] + ex_, ax);
            ay = fmaf(exv, vf[1] + ey_, ay);
        };

        for (int cb = rs; cb < re; cb += 64) {
            int cnum = re - cb; if (cnum > 64) cnum = 64;
            int mi = cb + lane;
            int sv = 0;
            float2 av = make_float2(0.f, 0.f);
            if (mi < re) {
                sv = esrc[mi];
                av = *(const float2*)&eat2[2 * (size_t)mi];
            }
            int base = 0;
            for (; base + 8 <= cnum; base += 8) {
                int s[8]; float eax[8], eay[8];
#pragma unroll
                for (int j = 0; j < 8; j++) {
                    s[j] = __shfl(sv, base + j);
                    eax[j] = __shfl(av.x, base + j);
                    eay[j] = __shfl(av.y, base + j);
                }
                unsigned int kk[8];
#pragma unroll
                for (int j = 0; j < 8; j++)
                    kk[j] = kvb[(size_t)s[j] * 64 + lane];
#pragma unroll
                for (int j = 0; j < 8; j++) edge(eax[j], eay[j], kk[j]);
            }
            for (; base < cnum; ++base) {
                int s0 = __shfl(sv, base);
                float ex0 = __shfl(av.x, base);
                float ey0 = __shfl(av.y, base);
                unsigned int k0 = kvb[(size_t)s0 * 64 + lane];
                edge(ex0, ey0, k0);
            }
        }

        float rden = 1.f / (den + 1e-16f);
        ax *= rden; ay *= rden;
        // beta gate
        float2 xv = *(const float2*)&xr[(size_t)n * 128 + ch];
        float gp = ax * wb_o.x + ay * wb_o.y + xv.x * wb_r.x + xv.y * wb_r.y
                 + (ax - xv.x) * wb_d.x + (ay - xv.y) * wb_d.y;
        gp += __shfl_xor(gp, 1);
        gp += __shfl_xor(gp, 2);
        gp += __shfl_xor(gp, 4);
        gp += __shfl_xor(gp, 8);
        gp += __shfl_xor(gp, 16);
        gp += __shfl_xor(gp, 32);
        float gate = 1.f / (1.f + __expf(-gp));
        float ox = gate * xv.x + (1.f - gate) * ax;
        float oy = gate * xv.y + (1.f - gate) * ay;
        *(float2*)&out2[(size_t)n * 128 + ch] = make_float2(ox, oy);
        bnsx += ox; bnsy += oy;
        bnqx = fmaf(ox, ox, bnqx); bnqy = fmaf(oy, oy, bnqy);
    }
    // block-level BN partial reduce
    __shared__ float s_sum[2][256], s_sq[2][256];
    s_sum[0][t] = bnsx; s_sum[1][t] = bnsy;
    s_sq[0][t] = bnqx;  s_sq[1][t] = bnqy;
    __syncthreads();
    if (t < 64) {
        float sx = s_sum[0][t] + s_sum[0][64 + t] + s_sum[0][128 + t] + s_sum[0][192 + t];
        float sy = s_sum[1][t] + s_sum[1][64 + t] + s_sum[1][128 + t] + s_sum[1][192 + t];
        float qx = s_sq[0][t] + s_sq[0][64 + t] + s_sq[0][128 + t] + s_sq[0][192 + t];
        float qy = s_sq[1][t] + s_sq[1][64 + t] + s_sq[1][128 + t] + s_sq[1][192 + t];
        int c = 2 * t;
        atomicAdd(&bn_accum[c], sx);
        atomicAdd(&bn_accum[c + 1], sy);
        atomicAdd(&bn_accum[128 + c], qx);
        atomicAdd(&bn_accum[128 + c + 1], qy);
    }
}

// ------- readout: BN affine+ELU+dot(Wout), 4 prefetched loads/wave, LDS per-graph
//         accumulate, one flush per block -------
__global__ __launch_bounds__(256) void k_pool(const float* __restrict__ x,
                                              const float* __restrict__ bn_acc,
                                              const float* __restrict__ gamma,
                                              const float* __restrict__ beta,
                                              const float* __restrict__ Wout,
                                              const int* __restrict__ batch,
                                              float* __restrict__ gsum, int* __restrict__ gcnt) {
    __shared__ float lsum[NGRAPH];
    __shared__ int lcnt[NGRAPH];
    __shared__ float ab_s[256];
    int t = threadIdx.x;
    if (t < NGRAPH) { lsum[t] = 0.f; lcnt[t] = 0; }
    if (t < 128) {
        float mu = bn_acc[t] * (1.f / NN);
        float var = bn_acc[128 + t] * (1.f / NN) - mu * mu;
        float inv = rsqrtf(var + 1e-5f);
        float a = inv * gamma[t];
        ab_s[t] = a;
        ab_s[128 + t] = beta[t] - mu * a;
    }
    __syncthreads();
    int lane = t & 63;
    int wid = t >> 6;
    int ch = lane * 2;
    float2 wo = *(const float2*)&Wout[ch];
    float2 a = *(const float2*)&ab_s[ch];
    float2 b = *(const float2*)&ab_s[128 + ch];
    int base = blockIdx.x * 16 + wid * 4;
    float2 xv[4];
#pragma unroll
    for (int i = 0; i < 4; i++) {          // issue all 4 loads before any use
        int n = base + i;
        xv[i] = (n < NN) ? *(const float2*)&x[(size_t)n * 128 + ch]
                         : make_float2(0.f, 0.f);
    }
#pragma unroll
    for (int i = 0; i < 4; i++) {
        int n = base + i;
        if (n < NN) {
            float z0 = fmaf(xv[i].x, a.x, b.x); z0 = z0 > 0.f ? z0 : expm1f(z0);
            float z1 = fmaf(xv[i].y, a.y, b.y); z1 = z1 > 0.f ? z1 : expm1f(z1);
            float p = z0 * wo.x + z1 * wo.y;
            p += __shfl_xor(p, 1);
            p += __shfl_xor(p, 2);
            p += __shfl_xor(p, 4);
            p += __shfl_xor(p, 8);
            p += __shfl_xor(p, 16);
            p += __shfl_xor(p, 32);
            if (lane == 0) {
                int g = batch[n];
                atomicAdd(&lsum[g], p);
                atomicAdd(&lcnt[g], 1);
            }
        }
    }
    __syncthreads();
    if (t < NGRAPH && lcnt[t] > 0) {
        atomicAdd(&gsum[t], lsum[t]);
        atomicAdd(&gcnt[t], lcnt[t]);
    }
}

__global__ void k_final(const float* __restrict__ gsum, const int* __restrict__ gcnt,
                        const float* __restrict__ bout, const float* __restrict__ obias,
                        float* __restrict__ out) {
    int g = threadIdx.x;
    if (g < NGRAPH) out[g] = gsum[g] / fmaxf((float)gcnt[g], 1.f) + bout[0] + obias[0];
}

extern "C" void kernel_launch(void* const* d_in, const int* in_sizes, int n_in,
                              void* d_out, int out_size, void* d_ws, size_t ws_size,
                              hipStream_t stream) {
    const float* x_in       = (const float*)d_in[0];
    const int* eidx         = (const int*)d_in[1];
    const float* eattr      = (const float*)d_in[2];
    const int* batch        = (const int*)d_in[3];
    const float* Wq         = (const float*)d_in[4];
    const float* bq         = (const float*)d_in[5];
    const float* Wk         = (const float*)d_in[6];
    const float* bk         = (const float*)d_in[7];
    const float* Wv         = (const float*)d_in[8];
    const float* bv         = (const float*)d_in[9];
    const float* We         = (const float*)d_in[10];
    const float* be         = (const float*)d_in[11];
    const float* Wskip      = (const float*)d_in[12];
    const float* bskip      = (const float*)d_in[13];
    const float* Wbeta      = (const float*)d_in[14];
    const float* bn_gamma   = (const float*)d_in[15];
    const float* bn_beta    = (const float*)d_in[16];
    const float* Wout       = (const float*)d_in[17];
    const float* bout       = (const float*)d_in[18];
    const float* obias      = (const float*)d_in[19];
    float* out = (float*)d_out;

    char* ws = (char*)d_ws;
    size_t off = 0;
    auto alloc = [&](size_t bytes) -> void* {
        off = (off + 255) & ~(size_t)255;
        void* p = ws + off;
        off += bytes;
        return p;
    };
    const size_t NF = (size_t)NN * 128 * sizeof(float);
    float* xbuf    = (float*)alloc(NF);
    float* qb      = (float*)alloc(NF);
    float* xrb     = (float*)alloc(NF);
    unsigned int* kvb = (unsigned int*)alloc((size_t)NN * 64 * sizeof(unsigned int));
    _Float16* wt   = (_Float16*)alloc((size_t)12 * 16384 * sizeof(_Float16));
    int* row_ptr   = (int*)alloc((NN + 1) * sizeof(int));
    int* cnt       = (int*)alloc(NN * sizeof(int));
    int* esrc      = (int*)alloc(EE * sizeof(int));
    float* eat2    = (float*)alloc((size_t)EE * 2 * sizeof(float));
    float* bn_acc3 = (float*)alloc(3 * 256 * sizeof(float));
    float* gsum    = (float*)alloc(64 * sizeof(float));
    int* gcnt      = (int*)alloc(64 * sizeof(int));
    (void)ws_size; (void)n_in; (void)in_sizes; (void)out_size;

    // ---- CSR degree + weight prep, scan (also zeroes aux) ----
    hipMemsetAsync(cnt, 0, NN * sizeof(int), stream);
    k_degprep<<<3125 + 768, 256, 0, stream>>>(eidx, cnt, Wq, Wk, Wv, Wskip, wt);
    k_scan<<<1, 1024, 0, stream>>>(cnt, row_ptr, bn_acc3, gsum, gcnt);

    // ---- layer 0 GEMM + CSR scatter fused (independent work) ----
    k_gemm0scat<<<GEMM_TILES + 3125, 256, 0, stream>>>(
        x_in, wt, bq, bk, bv, bskip, qb, kvb, xrb,
        eidx, eattr, row_ptr, cnt, esrc, eat2);
    k_attn<<<3125, 256, 0, stream>>>(
        qb, kvb, xrb, esrc, eat2, row_ptr,
        We, be, Wbeta, xbuf, bn_acc3);

    // ---- layers 1,2 ----
    for (int l = 1; l < 3; ++l) {
        k_gemm4<<<GEMM_TILES, 256, 0, stream>>>(
            xbuf, wt + (size_t)l * 65536,
            bq + l * 128, bk + l * 128, bv + l * 128, bskip + l * 128,
            bn_acc3 + (l - 1) * 256, bn_gamma + (l - 1) * 128, bn_beta + (l - 1) * 128,
            qb, kvb, xrb);
        k_attn<<<3125, 256, 0, stream>>>(
            qb, kvb, xrb, esrc, eat2, row_ptr,
            We + (size_t)l * 256, be + l * 128, Wbeta + (size_t)l * 384,
            xbuf, bn_acc3 + l * 256);
    }

    // ---- readout (BN affine+ELU of layer-2 fused in) ----
    k_pool<<<(NN + 15) / 16, 256, 0, stream>>>(xbuf, bn_acc3 + 2 * 256,
                                               bn_gamma + 2 * 128, bn_beta + 2 * 128,
                                               Wout, batch, gsum, gcnt);
    k_final<<<1, 64, 0, stream>>>(gsum, gcnt, bout, obias, out);
}